// Round 8
// baseline (498.698 us; speedup 1.0000x reference)
//
#include <hip/hip_runtime.h>
#include <hip/hip_bf16.h>

typedef __hip_bfloat16 bf16;
typedef __attribute__((ext_vector_type(8))) __bf16 bf16x8;
typedef __attribute__((ext_vector_type(4))) float f32x4;

#define NB 8
#define SEQ 2048
#define CH 768
#define NH 12
#define HD 64
#define NL 32
#define BHT (NB*NH)       // 96
#define TOK (NB*SEQ)      // 16384
#define QK_SCALE 0.35355339059327379f  // 64^-0.25

#define BAR() __builtin_amdgcn_s_barrier()
#define WVM(n) __asm__ __volatile__("s_waitcnt vmcnt(" #n ")" ::: "memory")

// async global->LDS, 16B per lane; LDS dest = wave-uniform base + lane*16
__device__ __forceinline__ void async_ld16(const bf16* g, bf16* l) {
    unsigned loff = (unsigned)__builtin_amdgcn_readfirstlane((int)(unsigned)(uintptr_t)l);
    __builtin_amdgcn_global_load_lds(
        (const __attribute__((address_space(1))) unsigned*)(uintptr_t)g,
        (__attribute__((address_space(3))) unsigned*)(uintptr_t)loff, 16, 0, 0);
}

// ---------------- fused prep: x->bf16 + weight transposes + accumulator zeroing ----------------
#define PREP_G0 (TOK*CH/2048)        // 6144
#define PREP_G1 ((3*CH/32)*(CH/32))  // 1728
#define PREP_G2 ((CH/32)*(CH/32))    // 576
#define PREP_G3 BHT                  // 96 zero blocks (Ql, Kl, O, S)
__global__ __launch_bounds__(256) void prep(const float* __restrict__ x, bf16* __restrict__ xb,
                                            const float* __restrict__ w_qkv, bf16* __restrict__ wqkvT,
                                            const float* __restrict__ w_proj, bf16* __restrict__ wprojT,
                                            float* __restrict__ Ql, float* __restrict__ Kl,
                                            float* __restrict__ O, float* __restrict__ S) {
    __shared__ float tile[32][33];
    const int bid = blockIdx.x;
    const int t = threadIdx.x;
    if (bid < PREP_G0) {
        size_t i = ((size_t)bid * 256 + t) * 8;
        float4 a = *reinterpret_cast<const float4*>(x + i);
        float4 b = *reinterpret_cast<const float4*>(x + i + 4);
        alignas(16) bf16 tmp[8];
        tmp[0] = __float2bfloat16(a.x); tmp[1] = __float2bfloat16(a.y);
        tmp[2] = __float2bfloat16(a.z); tmp[3] = __float2bfloat16(a.w);
        tmp[4] = __float2bfloat16(b.x); tmp[5] = __float2bfloat16(b.y);
        tmp[6] = __float2bfloat16(b.z); tmp[7] = __float2bfloat16(b.w);
        *reinterpret_cast<uint4*>(xb + i) = *reinterpret_cast<const uint4*>(tmp);
        return;
    }
    if (bid >= PREP_G0 + PREP_G1 + PREP_G2) {
        int bh = bid - (PREP_G0 + PREP_G1 + PREP_G2);
        for (int e = t; e < 2048; e += 256) {
            Ql[(size_t)bh * 2048 + e] = 0.f;
            Kl[(size_t)bh * 2048 + e] = 0.f;
            O[(size_t)bh * 2048 + e] = 0.f;
        }
        if (t < 32) S[(size_t)bh * NL + t] = 0.f;
        return;
    }
    const float* in; bf16* outp; int Hrows, Wcols, bx, by;
    if (bid < PREP_G0 + PREP_G1) {
        int tb = bid - PREP_G0;
        in = w_qkv; outp = wqkvT; Hrows = CH; Wcols = 3 * CH;
        bx = (tb % (3 * CH / 32)) * 32; by = (tb / (3 * CH / 32)) * 32;
    } else {
        int tb = bid - PREP_G0 - PREP_G1;
        in = w_proj; outp = wprojT; Hrows = CH; Wcols = CH;
        bx = (tb % (CH / 32)) * 32; by = (tb / (CH / 32)) * 32;
    }
    int tx = t & 31, ty = t >> 5;   // 32 x 8
    for (int i = 0; i < 32; i += 8)
        tile[ty + i][tx] = in[(size_t)(by + ty + i) * Wcols + bx + tx];
    __syncthreads();
    for (int i = 0; i < 32; i += 8)
        outp[(size_t)(bx + ty + i) * Hrows + by + tx] = __float2bfloat16(tile[tx][ty + i]);
}

// ---------------- GEMM: C[M][N] = A[M][K] * Bt[N][K]^T ----------------
// 128x128 tile, BK=64, 8 waves as 2Mx2Nx2K: wave owns 64x64 x (K-half).
// K-split halves LDS bytes/MFMA (512 vs 597) AND keeps acc at 64 VGPR ->
// fits the 128-reg cap of 16 waves/CU (launch_bounds(512,4), LDS 64KB dbuf
// -> 2 blocks/CU). Pipeline (r7-proven): head: stage next tile's 4 chunks;
// body: 8 ds_read_b128 + 16 MFMA; tail: vmcnt(0)+s_barrier.
// Epilogue: cross-K reduction via LDS exchange (wk pairs swap acc halves,
// __syncthreads-fenced); wave then owns mi = wk*2+{0,1}. Landmark colsums
// become 2-way atomicAdd into zero-initialized Ql/Kl.
// LDS XOR-swizzle byte^=((row&7)<<4); read chunk index = wk*4+quad.
// XCD remap (r2-proven): xcd=p&7; j=p>>3; bn=j%gx; bm=(j/gx)*8+xcd.
// Grids: EPI=0: 18x128=2304; EPI=1: 6x128=768 (both %8==0).
template <int EPI>
__global__ __launch_bounds__(512, 4) void gemm_bt(
    const bf16* __restrict__ A, const bf16* __restrict__ Bt,
    int Nout, int Kdim,
    bf16* __restrict__ q, bf16* __restrict__ k, bf16* __restrict__ vt,
    float* __restrict__ Ql, float* __restrict__ Kl,
    float* __restrict__ outp, const float* __restrict__ bias_f) {
    __shared__ __align__(16) char smem[65536];
    bf16* AsP = (bf16*)smem;              // [2][8192] elems (32 KB)
    bf16* BsP = (bf16*)(smem + 32768);    // [2][8192] elems (32 KB)
    const int t = threadIdx.x;
    const int wave = t >> 6, lane = t & 63;
    const int quad = lane >> 4, l15 = lane & 15;
    const int wk = wave >> 2;             // K-half
    const int wr = (wave >> 1) & 1, wc = wave & 1;

    int p = blockIdx.y * gridDim.x + blockIdx.x;
    int xcd = p & 7, j = p >> 3;
    int gx = gridDim.x;
    int bn = j % gx;
    int bm = (j / gx) * 8 + xcd;
    const int bm0 = bm * 128;
    const int bn0 = bn * 128;

    const int T = Kdim >> 6;   // 12 K-tiles of 64

    // ---- staging: inverse-swizzled global source, linear LDS dest ----
    // chunk = 64 rows x 64 cols x 2B = 8KB = 512 threads x 16B.
    const int srow = t >> 3;                          // 0..63
    const int scol = (((t & 7) ^ (srow & 7)) << 3);
    const bf16* Abase = A + (size_t)(bm0 + srow) * Kdim + scol;
    const bf16* Bbase = Bt + (size_t)(bn0 + srow) * Kdim + scol;

    auto stA = [&](int kt, int c) {   // c = 0..1
        async_ld16(Abase + (size_t)(c * 64) * Kdim + kt * 64,
                   &AsP[(kt & 1) * 8192 + c * 4096 + t * 8]);
    };
    auto stB = [&](int kt, int c) {   // c = 0..1
        async_ld16(Bbase + (size_t)(c * 64) * Kdim + kt * 64,
                   &BsP[(kt & 1) * 8192 + c * 4096 + t * 8]);
    };

    const int swk = ((wk * 4 + quad) ^ (l15 & 7)) << 3;  // swizzled k-chunk (wave's K-half)
    const bf16* arow = &AsP[(wr * 64 + l15) * 64];
    const bf16* brow = &BsP[(wc * 64 + l15) * 64];

    f32x4 acc[4][4];
    const f32x4 zero4 = {0.f, 0.f, 0.f, 0.f};
    #pragma unroll
    for (int i = 0; i < 4; i++)
        #pragma unroll
        for (int jj = 0; jj < 4; jj++) acc[i][jj] = zero4;

    // ---- prologue ----
    stA(0, 0); stA(0, 1); stB(0, 0); stB(0, 1);
    WVM(0);
    BAR();

    for (int kt = 0; kt < T; kt++) {
        const bool nxt = (kt + 1 < T);
        const bf16* ab = arow + (kt & 1) * 8192;
        const bf16* bb = brow + (kt & 1) * 8192;

        if (nxt) { stA(kt + 1, 0); stA(kt + 1, 1); stB(kt + 1, 0); stB(kt + 1, 1); }

        bf16x8 a[4], b[4];
        #pragma unroll
        for (int mi = 0; mi < 4; mi++)
            a[mi] = *reinterpret_cast<const bf16x8*>(ab + mi * 1024 + swk);
        #pragma unroll
        for (int ni = 0; ni < 4; ni++)
            b[ni] = *reinterpret_cast<const bf16x8*>(bb + ni * 1024 + swk);

        __builtin_amdgcn_s_setprio(1);
        #pragma unroll
        for (int mi = 0; mi < 4; mi++)
            #pragma unroll
            for (int ni = 0; ni < 4; ni++)
                acc[mi][ni] = __builtin_amdgcn_mfma_f32_16x16x32_bf16(a[mi], b[ni], acc[mi][ni], 0, 0, 0);
        __builtin_amdgcn_s_setprio(0);

        if (nxt) { WVM(0); BAR(); }
    }

    // ---- cross-K reduction: wk pairs swap acc halves via LDS ----
    // wk=0 keeps mi{0,1}, sends mi{2,3}; wk=1 keeps mi{2,3}, sends mi{0,1}.
    float* xch = (float*)smem;
    const int wrwc = wr * 2 + wc;
    const int whalf = wk ^ 1;
    __syncthreads();   // all K-loop LDS reads done before overwrite
    #pragma unroll
    for (int m2 = 0; m2 < 2; m2++)
        #pragma unroll
        for (int ni = 0; ni < 4; ni++)
            *reinterpret_cast<f32x4*>(
                &xch[(wrwc * 2 + whalf) * 2048 + (m2 * 4 + ni) * 256 + lane * 4]) = acc[whalf * 2 + m2][ni];
    __syncthreads();
    #pragma unroll
    for (int m2 = 0; m2 < 2; m2++)
        #pragma unroll
        for (int ni = 0; ni < 4; ni++)
            acc[wk * 2 + m2][ni] += *reinterpret_cast<const f32x4*>(
                &xch[(wrwc * 2 + wk) * 2048 + (m2 * 4 + ni) * 256 + lane * 4]);
    // wave now owns final rows mi = wk*2 + {0,1}

    if (EPI == 0) {
        // BN=128: 768 % 128 == 0, tile entirely within Q, K, or V; wave = 1 head.
        const int which = bn0 / CH;                   // uniform
        const int rem0 = bn0 - which * CH + wc * 64;  // multiple of 64
        const int b = bm0 >> 11;                      // uniform
        const int nnb = (bm0 & 2047) + wr * 64;
        const int h = rem0 >> 6;                      // uniform per wave
        const int bh = b * NH + h;
        if (which < 2) {
            bf16* dstqk = (which == 0) ? q : k;
            float* dstl = (which == 0) ? Ql : Kl;
            const int la = nnb >> 6;                  // one landmark per wr-half
            #pragma unroll
            for (int ni = 0; ni < 4; ni++) {
                int dd = ni * 16 + l15;
                float colsum = 0.f;
                #pragma unroll
                for (int m2 = 0; m2 < 2; m2++) {
                    int mi = wk * 2 + m2;
                    int nn0 = nnb + mi * 16 + quad * 4;
                    #pragma unroll
                    for (int r = 0; r < 4; r++) {
                        float val = acc[mi][ni][r];
                        colsum += val;
                        dstqk[((size_t)bh * SEQ + nn0 + r) * HD + dd] = __float2bfloat16(val * QK_SCALE);
                    }
                }
                colsum += __shfl_xor(colsum, 16);
                colsum += __shfl_xor(colsum, 32);
                if (quad == 0)
                    atomicAdd(&dstl[((size_t)bh * NL + la) * HD + dd], colsum * (QK_SCALE / 64.f));
            }
        } else {
            // V transposed: vt[bh][dd][n], 8B vector stores (4 consecutive n)
            #pragma unroll
            for (int ni = 0; ni < 4; ni++) {
                int dd = ni * 16 + l15;
                #pragma unroll
                for (int m2 = 0; m2 < 2; m2++) {
                    int mi = wk * 2 + m2;
                    int nn0 = nnb + mi * 16 + quad * 4;
                    alignas(8) bf16 four[4];
                    #pragma unroll
                    for (int r = 0; r < 4; r++) four[r] = __float2bfloat16(acc[mi][ni][r]);
                    *reinterpret_cast<uint2*>(&vt[((size_t)bh * HD + dd) * SEQ + nn0]) =
                        *reinterpret_cast<const uint2*>(four);
                }
            }
        }
    } else {
        #pragma unroll
        for (int ni = 0; ni < 4; ni++) {
            int col = bn0 + wc * 64 + ni * 16 + l15;
            float bb = bias_f[col];
            #pragma unroll
            for (int m2 = 0; m2 < 2; m2++) {
                int mi = wk * 2 + m2;
                #pragma unroll
                for (int r = 0; r < 4; r++) {
                    int row = bm0 + wr * 64 + mi * 16 + quad * 4 + r;
                    outp[(size_t)row * Nout + col] = acc[mi][ni][r] + bb;
                }
            }
        }
    }
}

// ---------------- kernel_3 softmax + @V via MFMA, plus co-scheduled NS inverse ----------------
// grid (96, 5): y==0 -> Newton-Schulz -> Vinv[bh]; y==1..4 -> PV partials
// atomicAdd'ed into O[bh][32][64], S[bh][32] (zeroed in prep).
__device__ inline void mm32(float* Cm, const float* Am, const float* Bm, int t) {
    for (int e = t; e < 1024; e += 256) {
        int i = e >> 5, jj = e & 31;
        float s = 0.f;
        #pragma unroll
        for (int kk = 0; kk < 32; kk++) s += Am[i * 32 + kk] * Bm[kk * 32 + jj];
        Cm[e] = s;
    }
}

__global__ __launch_bounds__(256) void k3_pv(const float* __restrict__ Ql,
                                             const float* __restrict__ Klm,
                                             const bf16* __restrict__ Kb,
                                             const bf16* __restrict__ Vt,
                                             float* __restrict__ O,
                                             float* __restrict__ S,
                                             float* __restrict__ Vinv) {
    __shared__ __align__(16) char smem[69632];
    const int bh = blockIdx.x;
    const int t = threadIdx.x;

    if (blockIdx.y == 0) {
        float* K2 = (float*)smem;
        float* Vv = K2 + 1024;
        float* KV = K2 + 2048;
        float* Ta = K2 + 3072;
        float* Tb = K2 + 4096;
        float* red = K2 + 5120;       // 33 floats
        const float* ql = Ql + (size_t)bh * NL * HD;
        const float* kl = Klm + (size_t)bh * NL * HD;

        for (int e = t; e < 1024; e += 256) {
            int i = e >> 5, jj = e & 31;
            float s = 0.f;
            #pragma unroll 8
            for (int d = 0; d < 64; d++) s += ql[i * 64 + d] * kl[jj * 64 + d];
            K2[e] = s;
        }
        __syncthreads();
        if (t < 32) {
            float mx = -1e30f;
            for (int jj = 0; jj < 32; jj++) mx = fmaxf(mx, K2[t * 32 + jj]);
            float sm = 0.f;
            for (int jj = 0; jj < 32; jj++) { float e = __expf(K2[t * 32 + jj] - mx); K2[t * 32 + jj] = e; sm += e; }
            float inv = 1.f / sm;
            for (int jj = 0; jj < 32; jj++) K2[t * 32 + jj] *= inv;
        }
        __syncthreads();
        if (t < 32) {
            float cs = 0.f;
            for (int i = 0; i < 32; i++) cs += K2[i * 32 + t];
            red[t] = cs;
        }
        __syncthreads();
        if (t == 0) {
            float mx = red[0];
            for (int jj = 1; jj < 32; jj++) mx = fmaxf(mx, red[jj]);
            red[32] = mx;
        }
        __syncthreads();
        float invden = 1.f / red[32];
        for (int e = t; e < 1024; e += 256) {
            int i = e >> 5, jj = e & 31;
            Vv[e] = K2[jj * 32 + i] * invden;
        }
        __syncthreads();
        for (int it = 0; it < 6; it++) {
            mm32(KV, K2, Vv, t);
            __syncthreads();
            for (int e = t; e < 1024; e += 256) { int i = e >> 5, jj = e & 31; Ta[e] = ((i == jj) ? 7.f : 0.f) - KV[e]; }
            __syncthreads();
            mm32(Tb, KV, Ta, t);
            __syncthreads();
            for (int e = t; e < 1024; e += 256) { int i = e >> 5, jj = e & 31; Tb[e] = ((i == jj) ? 15.f : 0.f) - Tb[e]; }
            __syncthreads();
            mm32(Ta, KV, Tb, t);
            __syncthreads();
            for (int e = t; e < 1024; e += 256) { int i = e >> 5, jj = e & 31; Ta[e] = ((i == jj) ? 13.f : 0.f) - Ta[e]; }
            __syncthreads();
            mm32(Tb, Vv, Ta, t);
            __syncthreads();
            for (int e = t; e < 1024; e += 256) Vv[e] = 0.25f * Tb[e];
            __syncthreads();
        }
        for (int e = t; e < 1024; e += 256)
            Vinv[(size_t)bh * 1024 + e] = Vv[e];
        return;
    }

    // ---- PV partial blocks ----
    bf16* Pw0 = (bf16*)smem;                              // 4 * 32*136 bf16
    float* Ored0 = (float*)(smem + 34816);                // 4 * 32*65 f32
    float* Sred = (float*)(smem + 34816 + 33280);         // 128 f32
    const int cc = blockIdx.y - 1;
    const int n0 = cc * 512;
    const int w = t >> 6, lane = t & 63;
    const int quad = lane >> 4, l15 = lane & 15;

    const bf16* Kbh = Kb + (size_t)bh * SEQ * HD;
    const bf16* Vtb = Vt + (size_t)bh * HD * SEQ;

    bf16x8 af[2][2];
    #pragma unroll
    for (int mt = 0; mt < 2; mt++)
        #pragma unroll
        for (int kh = 0; kh < 2; kh++) {
            const float* src = Ql + (size_t)bh * NL * HD + (mt * 16 + l15) * 64 + kh * 32 + quad * 8;
            alignas(16) bf16 tmp[8];
            #pragma unroll
            for (int jj = 0; jj < 8; jj++) tmp[jj] = __float2bfloat16(src[jj]);
            af[mt][kh] = *reinterpret_cast<const bf16x8*>(tmp);
        }

    const f32x4 zero4 = {0.f, 0.f, 0.f, 0.f};
    f32x4 oacc[2][4];
    #pragma unroll
    for (int mt = 0; mt < 2; mt++)
        #pragma unroll
        for (int nd = 0; nd < 4; nd++) oacc[mt][nd] = zero4;
    float rs[2][4];
    #pragma unroll
    for (int mt = 0; mt < 2; mt++)
        #pragma unroll
        for (int r = 0; r < 4; r++) rs[mt][r] = 0.f;

    bf16* Pme = Pw0 + w * (32 * 136);

    #pragma unroll
    for (int h = 0; h < 2; h++) {
        f32x4 sacc[2][4];
        #pragma unroll
        for (int mt = 0; mt < 2; mt++)
            #pragma unroll
            for (int nt = 0; nt < 4; nt++) sacc[mt][nt] = zero4;
        #pragma unroll
        for (int nt = 0; nt < 4; nt++) {
            int n = n0 + w * 128 + h * 64 + nt * 16 + l15;
            bf16x8 kf0 = *reinterpret_cast<const bf16x8*>(&Kbh[(size_t)n * HD + quad * 8]);
            bf16x8 kf1 = *reinterpret_cast<const bf16x8*>(&Kbh[(size_t)n * HD + 32 + quad * 8]);
            #pragma unroll
            for (int mt = 0; mt < 2; mt++) {
                sacc[mt][nt] = __builtin_amdgcn_mfma_f32_16x16x32_bf16(af[mt][0], kf0, sacc[mt][nt], 0, 0, 0);
                sacc[mt][nt] = __builtin_amdgcn_mfma_f32_16x16x32_bf16(af[mt][1], kf1, sacc[mt][nt], 0, 0, 0);
            }
        }
        #pragma unroll
        for (int mt = 0; mt < 2; mt++)
            #pragma unroll
            for (int nt = 0; nt < 4; nt++)
                #pragma unroll
                for (int r = 0; r < 4; r++) {
                    float pv = __expf(sacc[mt][nt][r]);
                    rs[mt][r] += pv;
                    int row = mt * 16 + quad * 4 + r;
                    Pme[row * 136 + h * 64 + nt * 16 + l15] = __float2bfloat16(pv);
                }
    }
    __asm__ __volatile__("s_waitcnt lgkmcnt(0)" ::: "memory");

    #pragma unroll
    for (int kt = 0; kt < 4; kt++) {
        bf16x8 pa[2];
        pa[0] = *reinterpret_cast<const bf16x8*>(&Pme[l15 * 136 + kt * 32 + quad * 8]);
        pa[1] = *reinterpret_cast<const bf16x8*>(&Pme[(16 + l15) * 136 + kt * 32 + quad * 8]);
        int kbase = n0 + w * 128 + kt * 32 + quad * 8;
        #pragma unroll
        for (int nd = 0; nd < 4; nd++) {
            bf16x8 bv = *reinterpret_cast<const bf16x8*>(&Vtb[(size_t)(nd * 16 + l15) * SEQ + kbase]);
            oacc[0][nd] = __builtin_amdgcn_mfma_f32_16x16x32_bf16(pa[0], bv, oacc[0][nd], 0, 0, 0);
            oacc[1][nd] = __builtin_amdgcn_mfma_f32_16x16x32_bf16(pa[1], bv, oacc[1][nd], 0, 0, 0);
        }
    }

    #pragma unroll
    for (int mt = 0; mt < 2; mt++)
        #pragma unroll
        for (int r = 0; r < 4; r++) {
            float v = rs[mt][r];
            #pragma unroll
            for (int o = 1; o < 16; o <<= 1) v += __shfl_xor(v, o);
            rs[mt][r] = v;
        }
    if (l15 == 0)
        #pragma unroll
        for (int mt = 0; mt < 2; mt++)
            #pragma unroll
            for (int r = 0; r < 4; r++)
                Sred[w * 32 + mt * 16 + quad * 4 + r] = rs[mt][r];
    #pragma unroll
    for (int mt = 0; mt < 2; mt++)
        #pragma unroll
        for (int nd = 0; nd < 4; nd++)
            #pragma unroll
            for (int r = 0; r < 4; r++)
                Ored0[w * (32 * 65) + (mt * 16 + quad * 4 + r) * 65 + nd * 16 + l15] = oacc[mt][nd][r];
    __syncthreads();

    float* Op = O + (size_t)bh * (NL * HD);
    for (int e = t; e < 2048; e += 256) {
        int m = e >> 6, dd = e & 63;
        float s = Ored0[0 * (32 * 65) + m * 65 + dd] + Ored0[1 * (32 * 65) + m * 65 + dd] +
                  Ored0[2 * (32 * 65) + m * 65 + dd] + Ored0[3 * (32 * 65) + m * 65 + dd];
        atomicAdd(&Op[e], s);
    }
    if (t < 32)
        atomicAdd(&S[(size_t)bh * NL + t], Sred[t] + Sred[32 + t] + Sred[64 + t] + Sred[96 + t]);
}

// ---------------- fused: W2 = Vinv @ (O/S); Xp = softmax(Q Kl^T) @ W2 ----------------
__global__ __launch_bounds__(256) void rows_fused(const bf16* __restrict__ Qb,
                                                  const float* __restrict__ Kl,
                                                  const float* __restrict__ Vinv,
                                                  const float* __restrict__ O,
                                                  const float* __restrict__ S,
                                                  bf16* __restrict__ Xp) {
    __shared__ __align__(16) char sm[20480];
    bf16* Klb = (bf16*)sm;              // 2048 bf16 (4KB)
    bf16* W2t = (bf16*)(sm + 4096);     // 2048 bf16 (4KB)
    float* VvT = (float*)(sm + 8192);   // 1024 f32 (4KB)   [scratch]
    float* K3n = (float*)(sm + 12288);  // 2048 f32 (8KB)   [scratch]
    bf16* Pw0 = (bf16*)(sm + 8192);     // 4*32*40 bf16 (10KB), overlays scratch after W2t built
    const int bh = blockIdx.x, tile = blockIdx.y;
    const int t = threadIdx.x, w = t >> 6, lane = t & 63;
    const int quad = lane >> 4, l15 = lane & 15;

    {
        const float* ksrc = Kl + (size_t)bh * NL * HD;
        int e0 = t * 8;
        #pragma unroll
        for (int jj = 0; jj < 8; jj++) Klb[e0 + jj] = __float2bfloat16(ksrc[e0 + jj]);
        // Vinv transposed into LDS (VvT[k][i] = Vinv[i][k]) for conflict-free compute
        for (int e = t; e < 1024; e += 256)
            VvT[e] = Vinv[(size_t)bh * 1024 + (e & 31) * 32 + (e >> 5)];
        const float* Obh = O + (size_t)bh * 2048;
        const float* Sbh = S + (size_t)bh * NL;
        for (int e = t; e < 2048; e += 256)
            K3n[e] = Obh[e] * (1.f / Sbh[e >> 6]);
    }
    __syncthreads();
    // W2t[dd*32 + i] = sum_k Vinv[i][k] * K3n[k][dd]
    for (int e = t; e < 2048; e += 256) {
        int dd = e >> 5, i = e & 31;
        float s = 0.f;
        #pragma unroll
        for (int kk = 0; kk < 32; kk++) s += VvT[kk * 32 + i] * K3n[kk * 64 + dd];
        W2t[e] = __float2bfloat16(s);
    }
    __syncthreads();

    const int b = bh / NH, h = bh - b * NH;
    const int row0 = tile * 128 + w * 32;
    const bf16* qbase = Qb + ((size_t)bh * SEQ + row0) * HD;

    const f32x4 zero4 = {0.f, 0.f, 0.f, 0.f};
    f32x4 sacc[2][2];
    #pragma unroll
    for (int mt = 0; mt < 2; mt++)
        #pragma unroll
        for (int nt = 0; nt < 2; nt++) sacc[mt][nt] = zero4;
    #pragma unroll
    for (int kh = 0; kh < 2; kh++) {
        bf16x8 bk0 = *reinterpret_cast<const bf16x8*>(&Klb[(l15) * 64 + kh * 32 + quad * 8]);
        bf16x8 bk1 = *reinterpret_cast<const bf16x8*>(&Klb[(16 + l15) * 64 + kh * 32 + quad * 8]);
        #pragma unroll
        for (int mt = 0; mt < 2; mt++) {
            bf16x8 aq = *reinterpret_cast<const bf16x8*>(&qbase[(size_t)(mt * 16 + l15) * HD + kh * 32 + quad * 8]);
            sacc[mt][0] = __builtin_amdgcn_mfma_f32_16x16x32_bf16(aq, bk0, sacc[mt][0], 0, 0, 0);
            sacc[mt][1] = __builtin_amdgcn_mfma_f32_16x16x32_bf16(aq, bk1, sacc[mt][1], 0, 0, 0);
        }
    }

    float invs[2][4];
    bf16* Pme = Pw0 + w * (32 * 40);
    #pragma unroll
    for (int mt = 0; mt < 2; mt++)
        #pragma unroll
        for (int r = 0; r < 4; r++) {
            float v0 = __expf(sacc[mt][0][r]);
            float v1 = __expf(sacc[mt][1][r]);
            int row = mt * 16 + quad * 4 + r;
            Pme[row * 40 + l15] = __float2bfloat16(v0);
            Pme[row * 40 + 16 + l15] = __float2bfloat16(v1);
            float v = v0 + v1;
            #pragma unroll
            for (int o = 1; o < 16; o <<= 1) v += __shfl_xor(v, o);
            invs[mt][r] = 1.f / v;
        }
    __asm__ __volatile__("s_waitcnt lgkmcnt(0)" ::: "memory");

    f32x4 oacc[2][4];
    #pragma unroll
    for (int mt = 0; mt < 2; mt++)
        #pragma unroll
        for (int nd = 0; nd < 4; nd++) oacc[mt][nd] = zero4;
    bf16x8 pa[2];
    pa[0] = *reinterpret_cast<const bf16x8*>(&Pme[l15 * 40 + quad * 8]);
    pa[1] = *reinterpret_cast<const bf16x8*>(&Pme[(16 + l15) * 40 + quad * 8]);
    #pragma unroll
    for (int nd = 0; nd < 4; nd++) {
        bf16x8 bw = *reinterpret_cast<const bf16x8*>(&W2t[(nd * 16 + l15) * 32 + quad * 8]);
        oacc[0][nd] = __builtin_amdgcn_mfma_f32_16x16x32_bf16(pa[0], bw, oacc[0][nd], 0, 0, 0);
        oacc[1][nd] = __builtin_amdgcn_mfma_f32_16x16x32_bf16(pa[1], bw, oacc[1][nd], 0, 0, 0);
    }

    #pragma unroll
    for (int mt = 0; mt < 2; mt++)
        #pragma unroll
        for (int nd = 0; nd < 4; nd++)
            #pragma unroll
            for (int r = 0; r < 4; r++) {
                int row = row0 + mt * 16 + quad * 4 + r;
                Xp[((size_t)(b * SEQ + row)) * CH + h * 64 + nd * 16 + l15] =
                    __float2bfloat16(oacc[mt][nd][r] * invs[mt][r]);
            }
}

extern "C" void kernel_launch(void* const* d_in, const int* in_sizes, int n_in,
                              void* d_out, int out_size, void* d_ws, size_t ws_size,
                              hipStream_t stream) {
    const float* x      = (const float*)d_in[0];
    const float* w_qkv  = (const float*)d_in[1];
    const float* w_proj = (const float*)d_in[2];
    const float* b_proj = (const float*)d_in[3];
    float* out = (float*)d_out;

    char* ws = (char*)d_ws;
    size_t off = 0;
    auto alloc = [&](size_t bytes) -> void* {
        void* p = ws + off;
        off += (bytes + 255) & ~(size_t)255;
        return p;
    };
    bf16* wqkvT  = (bf16*)alloc((size_t)3 * CH * CH * 2);
    bf16* wprojT = (bf16*)alloc((size_t)CH * CH * 2);
    bf16* Qb     = (bf16*)alloc((size_t)BHT * SEQ * HD * 2);
    bf16* Kb     = (bf16*)alloc((size_t)BHT * SEQ * HD * 2);
    bf16* Vt     = (bf16*)alloc((size_t)BHT * SEQ * HD * 2);
    float* Ql    = (float*)alloc((size_t)BHT * NL * HD * 4);
    float* Kl    = (float*)alloc((size_t)BHT * NL * HD * 4);
    float* Vinv  = (float*)alloc((size_t)BHT * NL * NL * 4);
    float* O     = (float*)alloc((size_t)BHT * NL * HD * 4);
    float* S     = (float*)alloc((size_t)BHT * NL * 4);
    bf16* Xp     = (bf16*)alloc((size_t)TOK * CH * 2);  // aliased: xb before rows_fused
    if (ws_size < off) return;
    bf16* xb = Xp;

    prep<<<PREP_G0 + PREP_G1 + PREP_G2 + PREP_G3, 256, 0, stream>>>(
        x, xb, w_qkv, wqkvT, w_proj, wprojT, Ql, Kl, O, S);

    gemm_bt<0><<<dim3((3 * CH) / 128, TOK / 128), 512, 0, stream>>>(
        xb, wqkvT, 3 * CH, CH, Qb, Kb, Vt, Ql, Kl, nullptr, nullptr);

    k3_pv<<<dim3(BHT, 5), 256, 0, stream>>>(Ql, Kl, Kb, Vt, O, S, Vinv);
    rows_fused<<<dim3(BHT, SEQ / 128), 256, 0, stream>>>(Qb, Kl, Vinv, O, S, Xp);

    gemm_bt<1><<<dim3(CH / 128, TOK / 128), 512, 0, stream>>>(
        Xp, wprojT, CH, CH, nullptr, nullptr, nullptr, nullptr, nullptr, out, b_proj);
}

// Round 9
// 263.704 us; speedup vs baseline: 1.8911x; 1.8911x over previous
//
#include <hip/hip_runtime.h>
#include <hip/hip_bf16.h>

typedef __hip_bfloat16 bf16;
typedef __attribute__((ext_vector_type(8))) __bf16 bf16x8;
typedef __attribute__((ext_vector_type(4))) float f32x4;

#define NB 8
#define SEQ 2048
#define CH 768
#define NH 12
#define HD 64
#define NL 32
#define BHT (NB*NH)       // 96
#define TOK (NB*SEQ)      // 16384
#define QK_SCALE 0.35355339059327379f  // 64^-0.25

#define BAR() __builtin_amdgcn_s_barrier()
#define WVM(n) __asm__ __volatile__("s_waitcnt vmcnt(" #n ")" ::: "memory")

// async global->LDS, 16B per lane; LDS dest = wave-uniform base + lane*16
__device__ __forceinline__ void async_ld16(const bf16* g, bf16* l) {
    unsigned loff = (unsigned)__builtin_amdgcn_readfirstlane((int)(unsigned)(uintptr_t)l);
    __builtin_amdgcn_global_load_lds(
        (const __attribute__((address_space(1))) unsigned*)(uintptr_t)g,
        (__attribute__((address_space(3))) unsigned*)(uintptr_t)loff, 16, 0, 0);
}

// ---------------- fused prep: x->bf16 + weight transposes + accumulator zeroing ----------------
#define PREP_G0 (TOK*CH/2048)        // 6144
#define PREP_G1 ((3*CH/32)*(CH/32))  // 1728
#define PREP_G2 ((CH/32)*(CH/32))    // 576
#define PREP_G3 BHT                  // 96 zero blocks (O, S; Ql/Kl zeroed too, harmless)
__global__ __launch_bounds__(256) void prep(const float* __restrict__ x, bf16* __restrict__ xb,
                                            const float* __restrict__ w_qkv, bf16* __restrict__ wqkvT,
                                            const float* __restrict__ w_proj, bf16* __restrict__ wprojT,
                                            float* __restrict__ Ql, float* __restrict__ Kl,
                                            float* __restrict__ O, float* __restrict__ S) {
    __shared__ float tile[32][33];
    const int bid = blockIdx.x;
    const int t = threadIdx.x;
    if (bid < PREP_G0) {
        size_t i = ((size_t)bid * 256 + t) * 8;
        float4 a = *reinterpret_cast<const float4*>(x + i);
        float4 b = *reinterpret_cast<const float4*>(x + i + 4);
        alignas(16) bf16 tmp[8];
        tmp[0] = __float2bfloat16(a.x); tmp[1] = __float2bfloat16(a.y);
        tmp[2] = __float2bfloat16(a.z); tmp[3] = __float2bfloat16(a.w);
        tmp[4] = __float2bfloat16(b.x); tmp[5] = __float2bfloat16(b.y);
        tmp[6] = __float2bfloat16(b.z); tmp[7] = __float2bfloat16(b.w);
        *reinterpret_cast<uint4*>(xb + i) = *reinterpret_cast<const uint4*>(tmp);
        return;
    }
    if (bid >= PREP_G0 + PREP_G1 + PREP_G2) {
        int bh = bid - (PREP_G0 + PREP_G1 + PREP_G2);
        for (int e = t; e < 2048; e += 256) {
            Ql[(size_t)bh * 2048 + e] = 0.f;
            Kl[(size_t)bh * 2048 + e] = 0.f;
            O[(size_t)bh * 2048 + e] = 0.f;
        }
        if (t < 32) S[(size_t)bh * NL + t] = 0.f;
        return;
    }
    const float* in; bf16* outp; int Hrows, Wcols, bx, by;
    if (bid < PREP_G0 + PREP_G1) {
        int tb = bid - PREP_G0;
        in = w_qkv; outp = wqkvT; Hrows = CH; Wcols = 3 * CH;
        bx = (tb % (3 * CH / 32)) * 32; by = (tb / (3 * CH / 32)) * 32;
    } else {
        int tb = bid - PREP_G0 - PREP_G1;
        in = w_proj; outp = wprojT; Hrows = CH; Wcols = CH;
        bx = (tb % (CH / 32)) * 32; by = (tb / (CH / 32)) * 32;
    }
    int tx = t & 31, ty = t >> 5;   // 32 x 8
    for (int i = 0; i < 32; i += 8)
        tile[ty + i][tx] = in[(size_t)(by + ty + i) * Wcols + bx + tx];
    __syncthreads();
    for (int i = 0; i < 32; i += 8)
        outp[(size_t)(bx + ty + i) * Hrows + by + tx] = __float2bfloat16(tile[tx][ty + i]);
}

// ---------------- GEMM: C[M][N] = A[M][K] * Bt[N][K]^T ----------------
// ROUND-7 PROVEN (68-71us, VGPR 64, 0 conflicts): 128x192 tile, BK=64,
// 8 waves (2Mx4N), wave owns 64x48 (acc 48 f32/lane).
// LDS 80KB dbuf; launch_bounds(512,4) -> <=128 VGPR -> 2 blocks/CU = 16 waves/CU.
// Pipeline, 1 barrier/tile: head: stage next tile's 5 chunks; body: 14
// ds_read_b128 + 24 MFMA; tail: vmcnt(0)+s_barrier.
// LDS XOR-swizzle byte^=((row&7)<<4): inverse-swizzled global source +
// linear global_load_lds dest + swizzled ds_read.
// XCD remap (r2-proven): xcd=p&7; j=p>>3; bn=j%gx; bm=(j/gx)*8+xcd.
template <int EPI>
__global__ __launch_bounds__(512, 4) void gemm_bt(
    const bf16* __restrict__ A, const bf16* __restrict__ Bt,
    int Nout, int Kdim,
    bf16* __restrict__ q, bf16* __restrict__ k, bf16* __restrict__ vt,
    float* __restrict__ Ql, float* __restrict__ Kl,
    float* __restrict__ outp, const float* __restrict__ bias_f) {
    __shared__ __align__(16) bf16 As[2][128 * 64];   // 32 KB
    __shared__ __align__(16) bf16 Bs[2][192 * 64];   // 48 KB
    const int t = threadIdx.x;
    const int wave = t >> 6, lane = t & 63;
    const int quad = lane >> 4, l15 = lane & 15;
    const int wr = wave >> 2, wc = wave & 3;   // 2x4; wave owns 64 rows x 48 cols

    int p = blockIdx.y * gridDim.x + blockIdx.x;
    int xcd = p & 7, j = p >> 3;
    int gx = gridDim.x;
    int bn = j % gx;
    int bm = (j / gx) * 8 + xcd;
    const int bm0 = bm * 128;
    const int bn0 = bn * 192;

    const int T = Kdim >> 6;   // 12 K-tiles of 64

    // ---- staging: inverse-swizzled global source, linear LDS dest ----
    // chunk = 64 rows x 64 cols x 2B = 8KB = 512 threads x 16B.
    const int srow = t >> 3;                          // 0..63
    const int scol = (((t & 7) ^ (srow & 7)) << 3);
    const bf16* Abase = A + (size_t)(bm0 + srow) * Kdim + scol;
    const bf16* Bbase = Bt + (size_t)(bn0 + srow) * Kdim + scol;

    auto stA = [&](int kt, int c) {   // c = 0..1
        async_ld16(Abase + (size_t)(c * 64) * Kdim + kt * 64,
                   &As[kt & 1][c * 4096 + t * 8]);
    };
    auto stB = [&](int kt, int c) {   // c = 0..2
        async_ld16(Bbase + (size_t)(c * 64) * Kdim + kt * 64,
                   &Bs[kt & 1][c * 4096 + t * 8]);
    };

    const int swk[2] = { (quad ^ (l15 & 7)) << 3, ((4 + quad) ^ (l15 & 7)) << 3 };
    const bf16* arow = &As[0][(wr * 64 + l15) * 64];
    const bf16* brow = &Bs[0][(wc * 48 + l15) * 64];

    f32x4 acc[4][3];
    const f32x4 zero4 = {0.f, 0.f, 0.f, 0.f};
    #pragma unroll
    for (int i = 0; i < 4; i++)
        #pragma unroll
        for (int jj = 0; jj < 3; jj++) acc[i][jj] = zero4;

    // ---- prologue: stage tile0, drain, barrier ----
    stA(0, 0); stA(0, 1); stB(0, 0); stB(0, 1); stB(0, 2);
    WVM(0);
    BAR();

    for (int kt = 0; kt < T; kt++) {
        const bool nxt = (kt + 1 < T);
        const bf16* ab = arow + (kt & 1) * 8192;
        const bf16* bb = brow + (kt & 1) * 12288;

        // head: issue next tile into the other buffer (read-complete since kt-1)
        if (nxt) { stA(kt + 1, 0); stA(kt + 1, 1); stB(kt + 1, 0); stB(kt + 1, 1); stB(kt + 1, 2); }

        // body: all fragments from current buffer
        bf16x8 a[4][2], b[3][2];
        #pragma unroll
        for (int mi = 0; mi < 4; mi++)
            #pragma unroll
            for (int kk = 0; kk < 2; kk++)
                a[mi][kk] = *reinterpret_cast<const bf16x8*>(ab + mi * 1024 + swk[kk]);
        #pragma unroll
        for (int ni = 0; ni < 3; ni++)
            #pragma unroll
            for (int kk = 0; kk < 2; kk++)
                b[ni][kk] = *reinterpret_cast<const bf16x8*>(bb + ni * 1024 + swk[kk]);

        __builtin_amdgcn_s_setprio(1);
        #pragma unroll
        for (int mi = 0; mi < 4; mi++)
            #pragma unroll
            for (int ni = 0; ni < 3; ni++)
                #pragma unroll
                for (int kk = 0; kk < 2; kk++)
                    acc[mi][ni] = __builtin_amdgcn_mfma_f32_16x16x32_bf16(a[mi][kk], b[ni][kk], acc[mi][ni], 0, 0, 0);
        __builtin_amdgcn_s_setprio(0);

        // tail: next tile resident for ALL waves after the barrier
        if (nxt) { WVM(0); BAR(); }
    }

    if (EPI == 0) {
        // 192-col tiles: 768 % 192 == 0, tile entirely within Q, K, or V.
        const int which = bn0 / CH;                   // uniform
        const int rem0 = bn0 - which * CH + wc * 48;  // wave col base within Q/K/V
        const int b = bm0 >> 11;                      // uniform
        const int nnb = (bm0 & 2047) + wr * 64;
        if (which < 2) {
            bf16* dstqk = (which == 0) ? q : k;
            float* dstl = (which == 0) ? Ql : Kl;
            const int la = nnb >> 6;                  // wave owns ONE landmark (64 rows)
            #pragma unroll
            for (int ni = 0; ni < 3; ni++) {
                int rem = rem0 + ni * 16;
                int h = rem >> 6;
                int dd = (rem & 63) + l15;
                int bh = b * NH + h;
                float colsum = 0.f;
                #pragma unroll
                for (int mi = 0; mi < 4; mi++) {
                    int nn0 = nnb + mi * 16 + quad * 4;
                    #pragma unroll
                    for (int r = 0; r < 4; r++) {
                        float val = acc[mi][ni][r];
                        colsum += val;
                        dstqk[((size_t)bh * SEQ + nn0 + r) * HD + dd] = __float2bfloat16(val * QK_SCALE);
                    }
                }
                colsum += __shfl_xor(colsum, 16);
                colsum += __shfl_xor(colsum, 32);
                if (quad == 0)
                    dstl[((size_t)bh * NL + la) * HD + dd] = colsum * (QK_SCALE / 64.f);
            }
        } else {
            // V transposed: vt[bh][dd][n], 8B vector stores (4 consecutive n)
            #pragma unroll
            for (int ni = 0; ni < 3; ni++) {
                int rem = rem0 + ni * 16;
                int h = rem >> 6;
                int dd = (rem & 63) + l15;
                int bh = b * NH + h;
                #pragma unroll
                for (int mi = 0; mi < 4; mi++) {
                    int nn0 = nnb + mi * 16 + quad * 4;
                    alignas(8) bf16 four[4];
                    #pragma unroll
                    for (int r = 0; r < 4; r++) four[r] = __float2bfloat16(acc[mi][ni][r]);
                    *reinterpret_cast<uint2*>(&vt[((size_t)bh * HD + dd) * SEQ + nn0]) =
                        *reinterpret_cast<const uint2*>(four);
                }
            }
        }
    } else {
        #pragma unroll
        for (int ni = 0; ni < 3; ni++) {
            int col = bn0 + wc * 48 + ni * 16 + l15;
            float bb = bias_f[col];
            #pragma unroll
            for (int mi = 0; mi < 4; mi++)
                #pragma unroll
                for (int r = 0; r < 4; r++) {
                    int row = bm0 + wr * 64 + mi * 16 + quad * 4 + r;
                    outp[(size_t)row * Nout + col] = acc[mi][ni][r] + bb;
                }
        }
    }
}

// ---------------- kernel_3 softmax + @V via MFMA, plus co-scheduled NS inverse ----------------
// grid (96, 5): y==0 -> Newton-Schulz -> Vinv[bh]; y==1..4 -> PV partials
// atomicAdd'ed into O[bh][32][64], S[bh][32] (zeroed in prep).
__device__ inline void mm32(float* Cm, const float* Am, const float* Bm, int t) {
    for (int e = t; e < 1024; e += 256) {
        int i = e >> 5, jj = e & 31;
        float s = 0.f;
        #pragma unroll
        for (int kk = 0; kk < 32; kk++) s += Am[i * 32 + kk] * Bm[kk * 32 + jj];
        Cm[e] = s;
    }
}

__global__ __launch_bounds__(256) void k3_pv(const float* __restrict__ Ql,
                                             const float* __restrict__ Klm,
                                             const bf16* __restrict__ Kb,
                                             const bf16* __restrict__ Vt,
                                             float* __restrict__ O,
                                             float* __restrict__ S,
                                             float* __restrict__ Vinv) {
    __shared__ __align__(16) char smem[69632];
    const int bh = blockIdx.x;
    const int t = threadIdx.x;

    if (blockIdx.y == 0) {
        float* K2 = (float*)smem;
        float* Vv = K2 + 1024;
        float* KV = K2 + 2048;
        float* Ta = K2 + 3072;
        float* Tb = K2 + 4096;
        float* red = K2 + 5120;       // 33 floats
        const float* ql = Ql + (size_t)bh * NL * HD;
        const float* kl = Klm + (size_t)bh * NL * HD;

        for (int e = t; e < 1024; e += 256) {
            int i = e >> 5, jj = e & 31;
            float s = 0.f;
            #pragma unroll 8
            for (int d = 0; d < 64; d++) s += ql[i * 64 + d] * kl[jj * 64 + d];
            K2[e] = s;
        }
        __syncthreads();
        if (t < 32) {
            float mx = -1e30f;
            for (int jj = 0; jj < 32; jj++) mx = fmaxf(mx, K2[t * 32 + jj]);
            float sm = 0.f;
            for (int jj = 0; jj < 32; jj++) { float e = __expf(K2[t * 32 + jj] - mx); K2[t * 32 + jj] = e; sm += e; }
            float inv = 1.f / sm;
            for (int jj = 0; jj < 32; jj++) K2[t * 32 + jj] *= inv;
        }
        __syncthreads();
        if (t < 32) {
            float cs = 0.f;
            for (int i = 0; i < 32; i++) cs += K2[i * 32 + t];
            red[t] = cs;
        }
        __syncthreads();
        if (t == 0) {
            float mx = red[0];
            for (int jj = 1; jj < 32; jj++) mx = fmaxf(mx, red[jj]);
            red[32] = mx;
        }
        __syncthreads();
        float invden = 1.f / red[32];
        for (int e = t; e < 1024; e += 256) {
            int i = e >> 5, jj = e & 31;
            Vv[e] = K2[jj * 32 + i] * invden;
        }
        __syncthreads();
        for (int it = 0; it < 6; it++) {
            mm32(KV, K2, Vv, t);
            __syncthreads();
            for (int e = t; e < 1024; e += 256) { int i = e >> 5, jj = e & 31; Ta[e] = ((i == jj) ? 7.f : 0.f) - KV[e]; }
            __syncthreads();
            mm32(Tb, KV, Ta, t);
            __syncthreads();
            for (int e = t; e < 1024; e += 256) { int i = e >> 5, jj = e & 31; Tb[e] = ((i == jj) ? 15.f : 0.f) - Tb[e]; }
            __syncthreads();
            mm32(Ta, KV, Tb, t);
            __syncthreads();
            for (int e = t; e < 1024; e += 256) { int i = e >> 5, jj = e & 31; Ta[e] = ((i == jj) ? 13.f : 0.f) - Ta[e]; }
            __syncthreads();
            mm32(Tb, Vv, Ta, t);
            __syncthreads();
            for (int e = t; e < 1024; e += 256) Vv[e] = 0.25f * Tb[e];
            __syncthreads();
        }
        for (int e = t; e < 1024; e += 256)
            Vinv[(size_t)bh * 1024 + e] = Vv[e];
        return;
    }

    // ---- PV partial blocks ----
    bf16* Pw0 = (bf16*)smem;                              // 4 * 32*136 bf16
    float* Ored0 = (float*)(smem + 34816);                // 4 * 32*65 f32
    float* Sred = (float*)(smem + 34816 + 33280);         // 128 f32
    const int cc = blockIdx.y - 1;
    const int n0 = cc * 512;
    const int w = t >> 6, lane = t & 63;
    const int quad = lane >> 4, l15 = lane & 15;

    const bf16* Kbh = Kb + (size_t)bh * SEQ * HD;
    const bf16* Vtb = Vt + (size_t)bh * HD * SEQ;

    bf16x8 af[2][2];
    #pragma unroll
    for (int mt = 0; mt < 2; mt++)
        #pragma unroll
        for (int kh = 0; kh < 2; kh++) {
            const float* src = Ql + (size_t)bh * NL * HD + (mt * 16 + l15) * 64 + kh * 32 + quad * 8;
            alignas(16) bf16 tmp[8];
            #pragma unroll
            for (int jj = 0; jj < 8; jj++) tmp[jj] = __float2bfloat16(src[jj]);
            af[mt][kh] = *reinterpret_cast<const bf16x8*>(tmp);
        }

    const f32x4 zero4 = {0.f, 0.f, 0.f, 0.f};
    f32x4 oacc[2][4];
    #pragma unroll
    for (int mt = 0; mt < 2; mt++)
        #pragma unroll
        for (int nd = 0; nd < 4; nd++) oacc[mt][nd] = zero4;
    float rs[2][4];
    #pragma unroll
    for (int mt = 0; mt < 2; mt++)
        #pragma unroll
        for (int r = 0; r < 4; r++) rs[mt][r] = 0.f;

    bf16* Pme = Pw0 + w * (32 * 136);

    #pragma unroll
    for (int h = 0; h < 2; h++) {
        f32x4 sacc[2][4];
        #pragma unroll
        for (int mt = 0; mt < 2; mt++)
            #pragma unroll
            for (int nt = 0; nt < 4; nt++) sacc[mt][nt] = zero4;
        #pragma unroll
        for (int nt = 0; nt < 4; nt++) {
            int n = n0 + w * 128 + h * 64 + nt * 16 + l15;
            bf16x8 kf0 = *reinterpret_cast<const bf16x8*>(&Kbh[(size_t)n * HD + quad * 8]);
            bf16x8 kf1 = *reinterpret_cast<const bf16x8*>(&Kbh[(size_t)n * HD + 32 + quad * 8]);
            #pragma unroll
            for (int mt = 0; mt < 2; mt++) {
                sacc[mt][nt] = __builtin_amdgcn_mfma_f32_16x16x32_bf16(af[mt][0], kf0, sacc[mt][nt], 0, 0, 0);
                sacc[mt][nt] = __builtin_amdgcn_mfma_f32_16x16x32_bf16(af[mt][1], kf1, sacc[mt][nt], 0, 0, 0);
            }
        }
        #pragma unroll
        for (int mt = 0; mt < 2; mt++)
            #pragma unroll
            for (int nt = 0; nt < 4; nt++)
                #pragma unroll
                for (int r = 0; r < 4; r++) {
                    float pv = __expf(sacc[mt][nt][r]);
                    rs[mt][r] += pv;
                    int row = mt * 16 + quad * 4 + r;
                    Pme[row * 136 + h * 64 + nt * 16 + l15] = __float2bfloat16(pv);
                }
    }
    __asm__ __volatile__("s_waitcnt lgkmcnt(0)" ::: "memory");

    #pragma unroll
    for (int kt = 0; kt < 4; kt++) {
        bf16x8 pa[2];
        pa[0] = *reinterpret_cast<const bf16x8*>(&Pme[l15 * 136 + kt * 32 + quad * 8]);
        pa[1] = *reinterpret_cast<const bf16x8*>(&Pme[(16 + l15) * 136 + kt * 32 + quad * 8]);
        int kbase = n0 + w * 128 + kt * 32 + quad * 8;
        #pragma unroll
        for (int nd = 0; nd < 4; nd++) {
            bf16x8 bv = *reinterpret_cast<const bf16x8*>(&Vtb[(size_t)(nd * 16 + l15) * SEQ + kbase]);
            oacc[0][nd] = __builtin_amdgcn_mfma_f32_16x16x32_bf16(pa[0], bv, oacc[0][nd], 0, 0, 0);
            oacc[1][nd] = __builtin_amdgcn_mfma_f32_16x16x32_bf16(pa[1], bv, oacc[1][nd], 0, 0, 0);
        }
    }

    #pragma unroll
    for (int mt = 0; mt < 2; mt++)
        #pragma unroll
        for (int r = 0; r < 4; r++) {
            float v = rs[mt][r];
            #pragma unroll
            for (int o = 1; o < 16; o <<= 1) v += __shfl_xor(v, o);
            rs[mt][r] = v;
        }
    if (l15 == 0)
        #pragma unroll
        for (int mt = 0; mt < 2; mt++)
            #pragma unroll
            for (int r = 0; r < 4; r++)
                Sred[w * 32 + mt * 16 + quad * 4 + r] = rs[mt][r];
    #pragma unroll
    for (int mt = 0; mt < 2; mt++)
        #pragma unroll
        for (int nd = 0; nd < 4; nd++)
            #pragma unroll
            for (int r = 0; r < 4; r++)
                Ored0[w * (32 * 65) + (mt * 16 + quad * 4 + r) * 65 + nd * 16 + l15] = oacc[mt][nd][r];
    __syncthreads();

    float* Op = O + (size_t)bh * (NL * HD);
    for (int e = t; e < 2048; e += 256) {
        int m = e >> 6, dd = e & 63;
        float s = Ored0[0 * (32 * 65) + m * 65 + dd] + Ored0[1 * (32 * 65) + m * 65 + dd] +
                  Ored0[2 * (32 * 65) + m * 65 + dd] + Ored0[3 * (32 * 65) + m * 65 + dd];
        atomicAdd(&Op[e], s);
    }
    if (t < 32)
        atomicAdd(&S[(size_t)bh * NL + t], Sred[t] + Sred[32 + t] + Sred[64 + t] + Sred[96 + t]);
}

// ---------------- fused: W2 = Vinv @ (O/S); Xp = softmax(Q Kl^T) @ W2 ----------------
__global__ __launch_bounds__(256) void rows_fused(const bf16* __restrict__ Qb,
                                                  const float* __restrict__ Kl,
                                                  const float* __restrict__ Vinv,
                                                  const float* __restrict__ O,
                                                  const float* __restrict__ S,
                                                  bf16* __restrict__ Xp) {
    __shared__ __align__(16) char sm[20480];
    bf16* Klb = (bf16*)sm;              // 2048 bf16 (4KB)
    bf16* W2t = (bf16*)(sm + 4096);     // 2048 bf16 (4KB)
    float* VvT = (float*)(sm + 8192);   // 1024 f32 (4KB)   [scratch]
    float* K3n = (float*)(sm + 12288);  // 2048 f32 (8KB)   [scratch]
    bf16* Pw0 = (bf16*)(sm + 8192);     // 4*32*40 bf16 (10KB), overlays scratch after W2t built
    const int bh = blockIdx.x, tile = blockIdx.y;
    const int t = threadIdx.x, w = t >> 6, lane = t & 63;
    const int quad = lane >> 4, l15 = lane & 15;

    {
        const float* ksrc = Kl + (size_t)bh * NL * HD;
        int e0 = t * 8;
        #pragma unroll
        for (int jj = 0; jj < 8; jj++) Klb[e0 + jj] = __float2bfloat16(ksrc[e0 + jj]);
        // Vinv transposed into LDS (VvT[k][i] = Vinv[i][k]) for conflict-free compute
        for (int e = t; e < 1024; e += 256)
            VvT[e] = Vinv[(size_t)bh * 1024 + (e & 31) * 32 + (e >> 5)];
        const float* Obh = O + (size_t)bh * 2048;
        const float* Sbh = S + (size_t)bh * NL;
        for (int e = t; e < 2048; e += 256)
            K3n[e] = Obh[e] * (1.f / Sbh[e >> 6]);
    }
    __syncthreads();
    // W2t[dd*32 + i] = sum_k Vinv[i][k] * K3n[k][dd]
    for (int e = t; e < 2048; e += 256) {
        int dd = e >> 5, i = e & 31;
        float s = 0.f;
        #pragma unroll
        for (int kk = 0; kk < 32; kk++) s += VvT[kk * 32 + i] * K3n[kk * 64 + dd];
        W2t[e] = __float2bfloat16(s);
    }
    __syncthreads();

    const int b = bh / NH, h = bh - b * NH;
    const int row0 = tile * 128 + w * 32;
    const bf16* qbase = Qb + ((size_t)bh * SEQ + row0) * HD;

    const f32x4 zero4 = {0.f, 0.f, 0.f, 0.f};
    f32x4 sacc[2][2];
    #pragma unroll
    for (int mt = 0; mt < 2; mt++)
        #pragma unroll
        for (int nt = 0; nt < 2; nt++) sacc[mt][nt] = zero4;
    #pragma unroll
    for (int kh = 0; kh < 2; kh++) {
        bf16x8 bk0 = *reinterpret_cast<const bf16x8*>(&Klb[(l15) * 64 + kh * 32 + quad * 8]);
        bf16x8 bk1 = *reinterpret_cast<const bf16x8*>(&Klb[(16 + l15) * 64 + kh * 32 + quad * 8]);
        #pragma unroll
        for (int mt = 0; mt < 2; mt++) {
            bf16x8 aq = *reinterpret_cast<const bf16x8*>(&qbase[(size_t)(mt * 16 + l15) * HD + kh * 32 + quad * 8]);
            sacc[mt][0] = __builtin_amdgcn_mfma_f32_16x16x32_bf16(aq, bk0, sacc[mt][0], 0, 0, 0);
            sacc[mt][1] = __builtin_amdgcn_mfma_f32_16x16x32_bf16(aq, bk1, sacc[mt][1], 0, 0, 0);
        }
    }

    float invs[2][4];
    bf16* Pme = Pw0 + w * (32 * 40);
    #pragma unroll
    for (int mt = 0; mt < 2; mt++)
        #pragma unroll
        for (int r = 0; r < 4; r++) {
            float v0 = __expf(sacc[mt][0][r]);
            float v1 = __expf(sacc[mt][1][r]);
            int row = mt * 16 + quad * 4 + r;
            Pme[row * 40 + l15] = __float2bfloat16(v0);
            Pme[row * 40 + 16 + l15] = __float2bfloat16(v1);
            float v = v0 + v1;
            #pragma unroll
            for (int o = 1; o < 16; o <<= 1) v += __shfl_xor(v, o);
            invs[mt][r] = 1.f / v;
        }
    __asm__ __volatile__("s_waitcnt lgkmcnt(0)" ::: "memory");

    f32x4 oacc[2][4];
    #pragma unroll
    for (int mt = 0; mt < 2; mt++)
        #pragma unroll
        for (int nd = 0; nd < 4; nd++) oacc[mt][nd] = zero4;
    bf16x8 pa[2];
    pa[0] = *reinterpret_cast<const bf16x8*>(&Pme[l15 * 40 + quad * 8]);
    pa[1] = *reinterpret_cast<const bf16x8*>(&Pme[(16 + l15) * 40 + quad * 8]);
    #pragma unroll
    for (int nd = 0; nd < 4; nd++) {
        bf16x8 bw = *reinterpret_cast<const bf16x8*>(&W2t[(nd * 16 + l15) * 32 + quad * 8]);
        oacc[0][nd] = __builtin_amdgcn_mfma_f32_16x16x32_bf16(pa[0], bw, oacc[0][nd], 0, 0, 0);
        oacc[1][nd] = __builtin_amdgcn_mfma_f32_16x16x32_bf16(pa[1], bw, oacc[1][nd], 0, 0, 0);
    }

    #pragma unroll
    for (int mt = 0; mt < 2; mt++)
        #pragma unroll
        for (int nd = 0; nd < 4; nd++)
            #pragma unroll
            for (int r = 0; r < 4; r++) {
                int row = row0 + mt * 16 + quad * 4 + r;
                Xp[((size_t)(b * SEQ + row)) * CH + h * 64 + nd * 16 + l15] =
                    __float2bfloat16(oacc[mt][nd][r] * invs[mt][r]);
            }
}

extern "C" void kernel_launch(void* const* d_in, const int* in_sizes, int n_in,
                              void* d_out, int out_size, void* d_ws, size_t ws_size,
                              hipStream_t stream) {
    const float* x      = (const float*)d_in[0];
    const float* w_qkv  = (const float*)d_in[1];
    const float* w_proj = (const float*)d_in[2];
    const float* b_proj = (const float*)d_in[3];
    float* out = (float*)d_out;

    char* ws = (char*)d_ws;
    size_t off = 0;
    auto alloc = [&](size_t bytes) -> void* {
        void* p = ws + off;
        off += (bytes + 255) & ~(size_t)255;
        return p;
    };
    bf16* wqkvT  = (bf16*)alloc((size_t)3 * CH * CH * 2);
    bf16* wprojT = (bf16*)alloc((size_t)CH * CH * 2);
    bf16* Qb     = (bf16*)alloc((size_t)BHT * SEQ * HD * 2);
    bf16* Kb     = (bf16*)alloc((size_t)BHT * SEQ * HD * 2);
    bf16* Vt     = (bf16*)alloc((size_t)BHT * SEQ * HD * 2);
    float* Ql    = (float*)alloc((size_t)BHT * NL * HD * 4);
    float* Kl    = (float*)alloc((size_t)BHT * NL * HD * 4);
    float* Vinv  = (float*)alloc((size_t)BHT * NL * NL * 4);
    float* O     = (float*)alloc((size_t)BHT * NL * HD * 4);
    float* S     = (float*)alloc((size_t)BHT * NL * 4);
    bf16* Xp     = (bf16*)alloc((size_t)TOK * CH * 2);  // aliased: xb before rows_fused
    if (ws_size < off) return;
    bf16* xb = Xp;

    prep<<<PREP_G0 + PREP_G1 + PREP_G2 + PREP_G3, 256, 0, stream>>>(
        x, xb, w_qkv, wqkvT, w_proj, wprojT, Ql, Kl, O, S);

    gemm_bt<0><<<dim3((3 * CH) / 192, TOK / 128), 512, 0, stream>>>(
        xb, wqkvT, 3 * CH, CH, Qb, Kb, Vt, Ql, Kl, nullptr, nullptr);

    k3_pv<<<dim3(BHT, 5), 256, 0, stream>>>(Ql, Kl, Kb, Vt, O, S, Vinv);
    rows_fused<<<dim3(BHT, SEQ / 128), 256, 0, stream>>>(Qb, Kl, Vinv, O, S, Xp);

    gemm_bt<1><<<dim3(CH / 192, TOK / 128), 512, 0, stream>>>(
        Xp, wprojT, CH, CH, nullptr, nullptr, nullptr, nullptr, nullptr, out, b_proj);
}

// Round 10
// 243.671 us; speedup vs baseline: 2.0466x; 1.0822x over previous
//
#include <hip/hip_runtime.h>
#include <hip/hip_bf16.h>

typedef __hip_bfloat16 bf16;
typedef __attribute__((ext_vector_type(8))) __bf16 bf16x8;
typedef __attribute__((ext_vector_type(4))) float f32x4;

#define NB 8
#define SEQ 2048
#define CH 768
#define NH 12
#define HD 64
#define NL 32
#define BHT (NB*NH)       // 96
#define TOK (NB*SEQ)      // 16384
#define QK_SCALE 0.35355339059327379f  // 64^-0.25

#define BAR() __builtin_amdgcn_s_barrier()
#define WVM(n) __asm__ __volatile__("s_waitcnt vmcnt(" #n ")" ::: "memory")

// async global->LDS, 16B per lane; LDS dest = wave-uniform base + lane*16
__device__ __forceinline__ void async_ld16(const bf16* g, bf16* l) {
    unsigned loff = (unsigned)__builtin_amdgcn_readfirstlane((int)(unsigned)(uintptr_t)l);
    __builtin_amdgcn_global_load_lds(
        (const __attribute__((address_space(1))) unsigned*)(uintptr_t)g,
        (__attribute__((address_space(3))) unsigned*)(uintptr_t)loff, 16, 0, 0);
}

// ---------------- fused prep: x->bf16 convert + both weight transposes ----------------
#define PREP_G0 (TOK*CH/2048)        // 6144
#define PREP_G1 ((3*CH/32)*(CH/32))  // 1728
#define PREP_G2 ((CH/32)*(CH/32))    // 576
__global__ __launch_bounds__(256) void prep(const float* __restrict__ x, bf16* __restrict__ xb,
                                            const float* __restrict__ w_qkv, bf16* __restrict__ wqkvT,
                                            const float* __restrict__ w_proj, bf16* __restrict__ wprojT) {
    __shared__ float tile[32][33];
    const int bid = blockIdx.x;
    const int t = threadIdx.x;
    if (bid < PREP_G0) {
        size_t i = ((size_t)bid * 256 + t) * 8;
        float4 a = *reinterpret_cast<const float4*>(x + i);
        float4 b = *reinterpret_cast<const float4*>(x + i + 4);
        alignas(16) bf16 tmp[8];
        tmp[0] = __float2bfloat16(a.x); tmp[1] = __float2bfloat16(a.y);
        tmp[2] = __float2bfloat16(a.z); tmp[3] = __float2bfloat16(a.w);
        tmp[4] = __float2bfloat16(b.x); tmp[5] = __float2bfloat16(b.y);
        tmp[6] = __float2bfloat16(b.z); tmp[7] = __float2bfloat16(b.w);
        *reinterpret_cast<uint4*>(xb + i) = *reinterpret_cast<const uint4*>(tmp);
        return;
    }
    const float* in; bf16* outp; int Hrows, Wcols, bx, by;
    if (bid < PREP_G0 + PREP_G1) {
        int tb = bid - PREP_G0;
        in = w_qkv; outp = wqkvT; Hrows = CH; Wcols = 3 * CH;
        bx = (tb % (3 * CH / 32)) * 32; by = (tb / (3 * CH / 32)) * 32;
    } else {
        int tb = bid - PREP_G0 - PREP_G1;
        in = w_proj; outp = wprojT; Hrows = CH; Wcols = CH;
        bx = (tb % (CH / 32)) * 32; by = (tb / (CH / 32)) * 32;
    }
    int tx = t & 31, ty = t >> 5;   // 32 x 8
    for (int i = 0; i < 32; i += 8)
        tile[ty + i][tx] = in[(size_t)(by + ty + i) * Wcols + bx + tx];
    __syncthreads();
    for (int i = 0; i < 32; i += 8)
        outp[(size_t)(bx + ty + i) * Hrows + by + tx] = __float2bfloat16(tile[tx][ty + i]);
}

// ---------------- GEMM: C[M][N] = A[M][K] * Bt[N][K]^T ----------------
// ROUND-7/9 PROVEN (66-71us, VGPR 64, 0 conflicts): 128x192 tile, BK=64,
// 8 waves (2Mx4N), wave owns 64x48 (acc 48 f32/lane).
// LDS 80KB dbuf; launch_bounds(512,4) -> <=128 VGPR -> 2 blocks/CU = 16 waves/CU.
// Pipeline, 1 barrier/tile: head: stage next tile's 5 chunks; body: 14
// ds_read_b128 + 24 MFMA; tail: vmcnt(0)+s_barrier.
// LDS XOR-swizzle byte^=((row&7)<<4): inverse-swizzled global source +
// linear global_load_lds dest + swizzled ds_read.
// XCD remap (r2-proven): xcd=p&7; j=p>>3; bn=j%gx; bm=(j/gx)*8+xcd.
template <int EPI>
__global__ __launch_bounds__(512, 4) void gemm_bt(
    const bf16* __restrict__ A, const bf16* __restrict__ Bt,
    int Nout, int Kdim,
    bf16* __restrict__ q, bf16* __restrict__ k, bf16* __restrict__ vt,
    float* __restrict__ Ql, float* __restrict__ Kl,
    float* __restrict__ outp, const float* __restrict__ bias_f) {
    __shared__ __align__(16) bf16 As[2][128 * 64];   // 32 KB
    __shared__ __align__(16) bf16 Bs[2][192 * 64];   // 48 KB
    const int t = threadIdx.x;
    const int wave = t >> 6, lane = t & 63;
    const int quad = lane >> 4, l15 = lane & 15;
    const int wr = wave >> 2, wc = wave & 3;   // 2x4; wave owns 64 rows x 48 cols

    int p = blockIdx.y * gridDim.x + blockIdx.x;
    int xcd = p & 7, j = p >> 3;
    int gx = gridDim.x;
    int bn = j % gx;
    int bm = (j / gx) * 8 + xcd;
    const int bm0 = bm * 128;
    const int bn0 = bn * 192;

    const int T = Kdim >> 6;   // 12 K-tiles of 64

    // ---- staging: inverse-swizzled global source, linear LDS dest ----
    // chunk = 64 rows x 64 cols x 2B = 8KB = 512 threads x 16B.
    const int srow = t >> 3;                          // 0..63
    const int scol = (((t & 7) ^ (srow & 7)) << 3);
    const bf16* Abase = A + (size_t)(bm0 + srow) * Kdim + scol;
    const bf16* Bbase = Bt + (size_t)(bn0 + srow) * Kdim + scol;

    auto stA = [&](int kt, int c) {   // c = 0..1
        async_ld16(Abase + (size_t)(c * 64) * Kdim + kt * 64,
                   &As[kt & 1][c * 4096 + t * 8]);
    };
    auto stB = [&](int kt, int c) {   // c = 0..2
        async_ld16(Bbase + (size_t)(c * 64) * Kdim + kt * 64,
                   &Bs[kt & 1][c * 4096 + t * 8]);
    };

    const int swk[2] = { (quad ^ (l15 & 7)) << 3, ((4 + quad) ^ (l15 & 7)) << 3 };
    const bf16* arow = &As[0][(wr * 64 + l15) * 64];
    const bf16* brow = &Bs[0][(wc * 48 + l15) * 64];

    f32x4 acc[4][3];
    const f32x4 zero4 = {0.f, 0.f, 0.f, 0.f};
    #pragma unroll
    for (int i = 0; i < 4; i++)
        #pragma unroll
        for (int jj = 0; jj < 3; jj++) acc[i][jj] = zero4;

    // ---- prologue: stage tile0, drain, barrier ----
    stA(0, 0); stA(0, 1); stB(0, 0); stB(0, 1); stB(0, 2);
    WVM(0);
    BAR();

    for (int kt = 0; kt < T; kt++) {
        const bool nxt = (kt + 1 < T);
        const bf16* ab = arow + (kt & 1) * 8192;
        const bf16* bb = brow + (kt & 1) * 12288;

        // head: issue next tile into the other buffer (read-complete since kt-1)
        if (nxt) { stA(kt + 1, 0); stA(kt + 1, 1); stB(kt + 1, 0); stB(kt + 1, 1); stB(kt + 1, 2); }

        // body: all fragments from current buffer
        bf16x8 a[4][2], b[3][2];
        #pragma unroll
        for (int mi = 0; mi < 4; mi++)
            #pragma unroll
            for (int kk = 0; kk < 2; kk++)
                a[mi][kk] = *reinterpret_cast<const bf16x8*>(ab + mi * 1024 + swk[kk]);
        #pragma unroll
        for (int ni = 0; ni < 3; ni++)
            #pragma unroll
            for (int kk = 0; kk < 2; kk++)
                b[ni][kk] = *reinterpret_cast<const bf16x8*>(bb + ni * 1024 + swk[kk]);

        __builtin_amdgcn_s_setprio(1);
        #pragma unroll
        for (int mi = 0; mi < 4; mi++)
            #pragma unroll
            for (int ni = 0; ni < 3; ni++)
                #pragma unroll
                for (int kk = 0; kk < 2; kk++)
                    acc[mi][ni] = __builtin_amdgcn_mfma_f32_16x16x32_bf16(a[mi][kk], b[ni][kk], acc[mi][ni], 0, 0, 0);
        __builtin_amdgcn_s_setprio(0);

        // tail: next tile resident for ALL waves after the barrier
        if (nxt) { WVM(0); BAR(); }
    }

    if (EPI == 0) {
        // 192-col tiles: 768 % 192 == 0, tile entirely within Q, K, or V.
        const int which = bn0 / CH;                   // uniform
        const int rem0 = bn0 - which * CH + wc * 48;  // wave col base within Q/K/V
        const int b = bm0 >> 11;                      // uniform
        const int nnb = (bm0 & 2047) + wr * 64;
        if (which < 2) {
            bf16* dstqk = (which == 0) ? q : k;
            float* dstl = (which == 0) ? Ql : Kl;
            const int la = nnb >> 6;                  // wave owns ONE landmark (64 rows)
            #pragma unroll
            for (int ni = 0; ni < 3; ni++) {
                int rem = rem0 + ni * 16;
                int h = rem >> 6;
                int dd = (rem & 63) + l15;
                int bh = b * NH + h;
                float colsum = 0.f;
                #pragma unroll
                for (int mi = 0; mi < 4; mi++) {
                    int nn0 = nnb + mi * 16 + quad * 4;
                    #pragma unroll
                    for (int r = 0; r < 4; r++) {
                        float val = acc[mi][ni][r];
                        colsum += val;
                        dstqk[((size_t)bh * SEQ + nn0 + r) * HD + dd] = __float2bfloat16(val * QK_SCALE);
                    }
                }
                colsum += __shfl_xor(colsum, 16);
                colsum += __shfl_xor(colsum, 32);
                if (quad == 0)
                    dstl[((size_t)bh * NL + la) * HD + dd] = colsum * (QK_SCALE / 64.f);
            }
        } else {
            // V transposed: vt[bh][dd][n], 8B vector stores (4 consecutive n)
            #pragma unroll
            for (int ni = 0; ni < 3; ni++) {
                int rem = rem0 + ni * 16;
                int h = rem >> 6;
                int dd = (rem & 63) + l15;
                int bh = b * NH + h;
                #pragma unroll
                for (int mi = 0; mi < 4; mi++) {
                    int nn0 = nnb + mi * 16 + quad * 4;
                    alignas(8) bf16 four[4];
                    #pragma unroll
                    for (int r = 0; r < 4; r++) four[r] = __float2bfloat16(acc[mi][ni][r]);
                    *reinterpret_cast<uint2*>(&vt[((size_t)bh * HD + dd) * SEQ + nn0]) =
                        *reinterpret_cast<const uint2*>(four);
                }
            }
        }
    } else {
        #pragma unroll
        for (int ni = 0; ni < 3; ni++) {
            int col = bn0 + wc * 48 + ni * 16 + l15;
            float bb = bias_f[col];
            #pragma unroll
            for (int mi = 0; mi < 4; mi++)
                #pragma unroll
                for (int r = 0; r < 4; r++) {
                    int row = bm0 + wr * 64 + mi * 16 + quad * 4 + r;
                    outp[(size_t)row * Nout + col] = acc[mi][ni][r] + bb;
                }
        }
    }
}

// ---------------- kernel_3 softmax + @V via MFMA, plus co-scheduled NS inverse ----------------
__device__ inline void mm32(float* Cm, const float* Am, const float* Bm, int t) {
    for (int e = t; e < 1024; e += 256) {
        int i = e >> 5, jj = e & 31;
        float s = 0.f;
        #pragma unroll
        for (int kk = 0; kk < 32; kk++) s += Am[i * 32 + kk] * Bm[kk * 32 + jj];
        Cm[e] = s;
    }
}

__global__ __launch_bounds__(256) void k3_pv(const float* __restrict__ Ql,
                                             const float* __restrict__ Klm,
                                             const bf16* __restrict__ Kb,
                                             const bf16* __restrict__ Vt,
                                             float* __restrict__ Opart,
                                             float* __restrict__ Spart,
                                             float* __restrict__ Vinv) {
    __shared__ __align__(16) char smem[69632];
    const int bh = blockIdx.x;
    const int t = threadIdx.x;

    if (blockIdx.y == 0) {
        float* K2 = (float*)smem;
        float* Vv = K2 + 1024;
        float* KV = K2 + 2048;
        float* Ta = K2 + 3072;
        float* Tb = K2 + 4096;
        float* red = K2 + 5120;       // 33 floats
        float* Qs = K2 + 5184;        // 2048 f32 (row-major [32][64])
        float* Ks = K2 + 7232;        // 2080 f32 (padded stride 65 -> conflict-free)
        const float* ql = Ql + (size_t)bh * NL * HD;
        const float* kl = Klm + (size_t)bh * NL * HD;

        // stage ql/kl via coalesced float4 (replaces 512 strided scalar
        // global loads per thread in the K2 build)
        for (int v = t; v < 512; v += 256) {
            float4 qv = reinterpret_cast<const float4*>(ql)[v];
            float4 kv = reinterpret_cast<const float4*>(kl)[v];
            int e = v * 4;
            Qs[e] = qv.x; Qs[e + 1] = qv.y; Qs[e + 2] = qv.z; Qs[e + 3] = qv.w;
            int jj = e >> 6, d = e & 63;
            float* kr = Ks + jj * 65 + d;
            kr[0] = kv.x; kr[1] = kv.y; kr[2] = kv.z; kr[3] = kv.w;
        }
        __syncthreads();
        for (int e = t; e < 1024; e += 256) {
            int i = e >> 5, jj = e & 31;
            float s = 0.f;
            #pragma unroll 8
            for (int d = 0; d < 64; d++) s += Qs[i * 64 + d] * Ks[jj * 65 + d];
            K2[e] = s;
        }
        __syncthreads();
        if (t < 32) {
            float mx = -1e30f;
            for (int jj = 0; jj < 32; jj++) mx = fmaxf(mx, K2[t * 32 + jj]);
            float sm = 0.f;
            for (int jj = 0; jj < 32; jj++) { float e = __expf(K2[t * 32 + jj] - mx); K2[t * 32 + jj] = e; sm += e; }
            float inv = 1.f / sm;
            for (int jj = 0; jj < 32; jj++) K2[t * 32 + jj] *= inv;
        }
        __syncthreads();
        if (t < 32) {
            float cs = 0.f;
            for (int i = 0; i < 32; i++) cs += K2[i * 32 + t];
            red[t] = cs;
        }
        __syncthreads();
        if (t == 0) {
            float mx = red[0];
            for (int jj = 1; jj < 32; jj++) mx = fmaxf(mx, red[jj]);
            red[32] = mx;
        }
        __syncthreads();
        float invden = 1.f / red[32];
        for (int e = t; e < 1024; e += 256) {
            int i = e >> 5, jj = e & 31;
            Vv[e] = K2[jj * 32 + i] * invden;
        }
        __syncthreads();
        for (int it = 0; it < 6; it++) {
            mm32(KV, K2, Vv, t);
            __syncthreads();
            for (int e = t; e < 1024; e += 256) { int i = e >> 5, jj = e & 31; Ta[e] = ((i == jj) ? 7.f : 0.f) - KV[e]; }
            __syncthreads();
            mm32(Tb, KV, Ta, t);
            __syncthreads();
            for (int e = t; e < 1024; e += 256) { int i = e >> 5, jj = e & 31; Tb[e] = ((i == jj) ? 15.f : 0.f) - Tb[e]; }
            __syncthreads();
            mm32(Ta, KV, Tb, t);
            __syncthreads();
            for (int e = t; e < 1024; e += 256) { int i = e >> 5, jj = e & 31; Ta[e] = ((i == jj) ? 13.f : 0.f) - Ta[e]; }
            __syncthreads();
            mm32(Tb, Vv, Ta, t);
            __syncthreads();
            for (int e = t; e < 1024; e += 256) Vv[e] = 0.25f * Tb[e];
            __syncthreads();
        }
        for (int e = t; e < 1024; e += 256)
            Vinv[(size_t)bh * 1024 + e] = Vv[e];
        return;
    }

    // ---- PV partial blocks ----
    bf16* Pw0 = (bf16*)smem;                              // 4 * 32*136 bf16
    float* Ored0 = (float*)(smem + 34816);                // 4 * 32*65 f32
    float* Sred = (float*)(smem + 34816 + 33280);         // 128 f32
    const int cc = blockIdx.y - 1;
    const int n0 = cc * 512;
    const int w = t >> 6, lane = t & 63;
    const int quad = lane >> 4, l15 = lane & 15;

    const bf16* Kbh = Kb + (size_t)bh * SEQ * HD;
    const bf16* Vtb = Vt + (size_t)bh * HD * SEQ;

    bf16x8 af[2][2];
    #pragma unroll
    for (int mt = 0; mt < 2; mt++)
        #pragma unroll
        for (int kh = 0; kh < 2; kh++) {
            const float* src = Ql + (size_t)bh * NL * HD + (mt * 16 + l15) * 64 + kh * 32 + quad * 8;
            alignas(16) bf16 tmp[8];
            #pragma unroll
            for (int jj = 0; jj < 8; jj++) tmp[jj] = __float2bfloat16(src[jj]);
            af[mt][kh] = *reinterpret_cast<const bf16x8*>(tmp);
        }

    const f32x4 zero4 = {0.f, 0.f, 0.f, 0.f};
    f32x4 oacc[2][4];
    #pragma unroll
    for (int mt = 0; mt < 2; mt++)
        #pragma unroll
        for (int nd = 0; nd < 4; nd++) oacc[mt][nd] = zero4;
    float rs[2][4];
    #pragma unroll
    for (int mt = 0; mt < 2; mt++)
        #pragma unroll
        for (int r = 0; r < 4; r++) rs[mt][r] = 0.f;

    bf16* Pme = Pw0 + w * (32 * 136);

    #pragma unroll
    for (int h = 0; h < 2; h++) {
        f32x4 sacc[2][4];
        #pragma unroll
        for (int mt = 0; mt < 2; mt++)
            #pragma unroll
            for (int nt = 0; nt < 4; nt++) sacc[mt][nt] = zero4;
        #pragma unroll
        for (int nt = 0; nt < 4; nt++) {
            int n = n0 + w * 128 + h * 64 + nt * 16 + l15;
            bf16x8 kf0 = *reinterpret_cast<const bf16x8*>(&Kbh[(size_t)n * HD + quad * 8]);
            bf16x8 kf1 = *reinterpret_cast<const bf16x8*>(&Kbh[(size_t)n * HD + 32 + quad * 8]);
            #pragma unroll
            for (int mt = 0; mt < 2; mt++) {
                sacc[mt][nt] = __builtin_amdgcn_mfma_f32_16x16x32_bf16(af[mt][0], kf0, sacc[mt][nt], 0, 0, 0);
                sacc[mt][nt] = __builtin_amdgcn_mfma_f32_16x16x32_bf16(af[mt][1], kf1, sacc[mt][nt], 0, 0, 0);
            }
        }
        #pragma unroll
        for (int mt = 0; mt < 2; mt++)
            #pragma unroll
            for (int nt = 0; nt < 4; nt++)
                #pragma unroll
                for (int r = 0; r < 4; r++) {
                    float pv = __expf(sacc[mt][nt][r]);
                    rs[mt][r] += pv;
                    int row = mt * 16 + quad * 4 + r;
                    Pme[row * 136 + h * 64 + nt * 16 + l15] = __float2bfloat16(pv);
                }
    }
    __asm__ __volatile__("s_waitcnt lgkmcnt(0)" ::: "memory");

    #pragma unroll
    for (int kt = 0; kt < 4; kt++) {
        bf16x8 pa[2];
        pa[0] = *reinterpret_cast<const bf16x8*>(&Pme[l15 * 136 + kt * 32 + quad * 8]);
        pa[1] = *reinterpret_cast<const bf16x8*>(&Pme[(16 + l15) * 136 + kt * 32 + quad * 8]);
        int kbase = n0 + w * 128 + kt * 32 + quad * 8;
        #pragma unroll
        for (int nd = 0; nd < 4; nd++) {
            bf16x8 bv = *reinterpret_cast<const bf16x8*>(&Vtb[(size_t)(nd * 16 + l15) * SEQ + kbase]);
            oacc[0][nd] = __builtin_amdgcn_mfma_f32_16x16x32_bf16(pa[0], bv, oacc[0][nd], 0, 0, 0);
            oacc[1][nd] = __builtin_amdgcn_mfma_f32_16x16x32_bf16(pa[1], bv, oacc[1][nd], 0, 0, 0);
        }
    }

    #pragma unroll
    for (int mt = 0; mt < 2; mt++)
        #pragma unroll
        for (int r = 0; r < 4; r++) {
            float v = rs[mt][r];
            #pragma unroll
            for (int o = 1; o < 16; o <<= 1) v += __shfl_xor(v, o);
            rs[mt][r] = v;
        }
    if (l15 == 0)
        #pragma unroll
        for (int mt = 0; mt < 2; mt++)
            #pragma unroll
            for (int r = 0; r < 4; r++)
                Sred[w * 32 + mt * 16 + quad * 4 + r] = rs[mt][r];
    #pragma unroll
    for (int mt = 0; mt < 2; mt++)
        #pragma unroll
        for (int nd = 0; nd < 4; nd++)
            #pragma unroll
            for (int r = 0; r < 4; r++)
                Ored0[w * (32 * 65) + (mt * 16 + quad * 4 + r) * 65 + nd * 16 + l15] = oacc[mt][nd][r];
    __syncthreads();

    float* Op = Opart + ((size_t)bh * 4 + cc) * (NL * HD);
    for (int e = t; e < 2048; e += 256) {
        int m = e >> 6, dd = e & 63;
        Op[e] = Ored0[0 * (32 * 65) + m * 65 + dd] + Ored0[1 * (32 * 65) + m * 65 + dd] +
                Ored0[2 * (32 * 65) + m * 65 + dd] + Ored0[3 * (32 * 65) + m * 65 + dd];
    }
    if (t < 32)
        Spart[((size_t)bh * 4 + cc) * NL + t] = Sred[t] + Sred[32 + t] + Sred[64 + t] + Sred[96 + t];
}

// ---------------- combine k3_pv partials + W2 = Vinv @ k3v ----------------
__global__ __launch_bounds__(256) void combine_w2(const float* __restrict__ Opart,
                                                  const float* __restrict__ Spart,
                                                  const float* __restrict__ Vinv,
                                                  float* __restrict__ W2) {
    __shared__ float K3[2048];
    __shared__ float Vv[1024];
    __shared__ float stot[32];
    const int bh = blockIdx.x;
    const int t = threadIdx.x;

    if (t < 32) {
        const float* sp = Spart + (size_t)bh * 4 * NL;
        stot[t] = sp[t] + sp[32 + t] + sp[64 + t] + sp[96 + t];
    }
    {
        const float* op = Opart + (size_t)bh * 4 * (NL * HD);
        for (int e = t; e < 2048; e += 256)
            K3[e] = op[e] + op[2048 + e] + op[4096 + e] + op[6144 + e];
    }
    for (int e = t; e < 1024; e += 256)
        Vv[e] = Vinv[(size_t)bh * 1024 + e];
    __syncthreads();
    for (int e = t; e < 2048; e += 256) K3[e] *= (1.f / stot[e >> 6]);
    __syncthreads();
    for (int e = t; e < 2048; e += 256) {
        int i = e >> 6, dd = e & 63;
        float s = 0.f;
        #pragma unroll
        for (int kk = 0; kk < 32; kk++) s += Vv[i * 32 + kk] * K3[kk * 64 + dd];
        W2[(size_t)bh * NL * HD + e] = s;
    }
}

// ---------------- fused: Xp = softmax(Q Kl^T) @ W2 via MFMA ----------------
__global__ __launch_bounds__(256) void rows_fused(const bf16* __restrict__ Qb,
                                                  const float* __restrict__ Kl,
                                                  const float* __restrict__ W2,
                                                  bf16* __restrict__ Xp) {
    __shared__ __align__(16) bf16 Klb[32 * 64];
    __shared__ __align__(16) bf16 W2t[64 * 32];
    __shared__ __align__(16) bf16 Pw[4][32 * 40];
    const int bh = blockIdx.x, tile = blockIdx.y;
    const int t = threadIdx.x, w = t >> 6, lane = t & 63;
    const int quad = lane >> 4, l15 = lane & 15;

    {
        const float* ksrc = Kl + (size_t)bh * NL * HD;
        const float* wsrc = W2 + (size_t)bh * NL * HD;
        for (int v = t; v < 512; v += 256) {
            float4 kv = reinterpret_cast<const float4*>(ksrc)[v];
            float4 wv = reinterpret_cast<const float4*>(wsrc)[v];
            int e = v * 4;
            Klb[e + 0] = __float2bfloat16(kv.x); Klb[e + 1] = __float2bfloat16(kv.y);
            Klb[e + 2] = __float2bfloat16(kv.z); Klb[e + 3] = __float2bfloat16(kv.w);
            int kk = e >> 6, dd = e & 63;
            W2t[(dd + 0) * 32 + kk] = __float2bfloat16(wv.x);
            W2t[(dd + 1) * 32 + kk] = __float2bfloat16(wv.y);
            W2t[(dd + 2) * 32 + kk] = __float2bfloat16(wv.z);
            W2t[(dd + 3) * 32 + kk] = __float2bfloat16(wv.w);
        }
    }
    __syncthreads();

    const int b = bh / NH, h = bh - b * NH;
    const int row0 = tile * 128 + w * 32;
    const bf16* qbase = Qb + ((size_t)bh * SEQ + row0) * HD;

    const f32x4 zero4 = {0.f, 0.f, 0.f, 0.f};
    f32x4 sacc[2][2];
    #pragma unroll
    for (int mt = 0; mt < 2; mt++)
        #pragma unroll
        for (int nt = 0; nt < 2; nt++) sacc[mt][nt] = zero4;
    #pragma unroll
    for (int kh = 0; kh < 2; kh++) {
        bf16x8 bk0 = *reinterpret_cast<const bf16x8*>(&Klb[(l15) * 64 + kh * 32 + quad * 8]);
        bf16x8 bk1 = *reinterpret_cast<const bf16x8*>(&Klb[(16 + l15) * 64 + kh * 32 + quad * 8]);
        #pragma unroll
        for (int mt = 0; mt < 2; mt++) {
            bf16x8 aq = *reinterpret_cast<const bf16x8*>(&qbase[(size_t)(mt * 16 + l15) * HD + kh * 32 + quad * 8]);
            sacc[mt][0] = __builtin_amdgcn_mfma_f32_16x16x32_bf16(aq, bk0, sacc[mt][0], 0, 0, 0);
            sacc[mt][1] = __builtin_amdgcn_mfma_f32_16x16x32_bf16(aq, bk1, sacc[mt][1], 0, 0, 0);
        }
    }

    float invs[2][4];
    bf16* Pme = &Pw[w][0];
    #pragma unroll
    for (int mt = 0; mt < 2; mt++)
        #pragma unroll
        for (int r = 0; r < 4; r++) {
            float v0 = __expf(sacc[mt][0][r]);
            float v1 = __expf(sacc[mt][1][r]);
            int row = mt * 16 + quad * 4 + r;
            Pme[row * 40 + l15] = __float2bfloat16(v0);
            Pme[row * 40 + 16 + l15] = __float2bfloat16(v1);
            float v = v0 + v1;
            #pragma unroll
            for (int o = 1; o < 16; o <<= 1) v += __shfl_xor(v, o);
            invs[mt][r] = 1.f / v;
        }
    __asm__ __volatile__("s_waitcnt lgkmcnt(0)" ::: "memory");

    f32x4 oacc[2][4];
    #pragma unroll
    for (int mt = 0; mt < 2; mt++)
        #pragma unroll
        for (int nd = 0; nd < 4; nd++) oacc[mt][nd] = zero4;
    bf16x8 pa[2];
    pa[0] = *reinterpret_cast<const bf16x8*>(&Pme[l15 * 40 + quad * 8]);
    pa[1] = *reinterpret_cast<const bf16x8*>(&Pme[(16 + l15) * 40 + quad * 8]);
    #pragma unroll
    for (int nd = 0; nd < 4; nd++) {
        bf16x8 bw = *reinterpret_cast<const bf16x8*>(&W2t[(nd * 16 + l15) * 32 + quad * 8]);
        oacc[0][nd] = __builtin_amdgcn_mfma_f32_16x16x32_bf16(pa[0], bw, oacc[0][nd], 0, 0, 0);
        oacc[1][nd] = __builtin_amdgcn_mfma_f32_16x16x32_bf16(pa[1], bw, oacc[1][nd], 0, 0, 0);
    }

    #pragma unroll
    for (int mt = 0; mt < 2; mt++)
        #pragma unroll
        for (int nd = 0; nd < 4; nd++)
            #pragma unroll
            for (int r = 0; r < 4; r++) {
                int row = row0 + mt * 16 + quad * 4 + r;
                Xp[((size_t)(b * SEQ + row)) * CH + h * 64 + nd * 16 + l15] =
                    __float2bfloat16(oacc[mt][nd][r] * invs[mt][r]);
            }
}

extern "C" void kernel_launch(void* const* d_in, const int* in_sizes, int n_in,
                              void* d_out, int out_size, void* d_ws, size_t ws_size,
                              hipStream_t stream) {
    const float* x      = (const float*)d_in[0];
    const float* w_qkv  = (const float*)d_in[1];
    const float* w_proj = (const float*)d_in[2];
    const float* b_proj = (const float*)d_in[3];
    float* out = (float*)d_out;

    char* ws = (char*)d_ws;
    size_t off = 0;
    auto alloc = [&](size_t bytes) -> void* {
        void* p = ws + off;
        off += (bytes + 255) & ~(size_t)255;
        return p;
    };
    bf16* wqkvT  = (bf16*)alloc((size_t)3 * CH * CH * 2);
    bf16* wprojT = (bf16*)alloc((size_t)CH * CH * 2);
    bf16* Qb     = (bf16*)alloc((size_t)BHT * SEQ * HD * 2);
    bf16* Kb     = (bf16*)alloc((size_t)BHT * SEQ * HD * 2);
    bf16* Vt     = (bf16*)alloc((size_t)BHT * SEQ * HD * 2);
    float* Ql    = (float*)alloc((size_t)BHT * NL * HD * 4);
    float* Kl    = (float*)alloc((size_t)BHT * NL * HD * 4);
    float* Opart = (float*)alloc((size_t)BHT * 4 * NL * HD * 4);
    float* Spart = (float*)alloc((size_t)BHT * 4 * NL * 4);
    float* Vinv  = (float*)alloc((size_t)BHT * NL * NL * 4);
    float* W2    = (float*)alloc((size_t)BHT * NL * HD * 4);
    bf16* Xp     = (bf16*)alloc((size_t)TOK * CH * 2);  // aliased: xb before rows_fused
    if (ws_size < off) return;
    bf16* xb = Xp;

    prep<<<PREP_G0 + PREP_G1 + PREP_G2, 256, 0, stream>>>(x, xb, w_qkv, wqkvT, w_proj, wprojT);

    gemm_bt<0><<<dim3((3 * CH) / 192, TOK / 128), 512, 0, stream>>>(
        xb, wqkvT, 3 * CH, CH, Qb, Kb, Vt, Ql, Kl, nullptr, nullptr);

    k3_pv<<<dim3(BHT, 5), 256, 0, stream>>>(Ql, Kl, Kb, Vt, Opart, Spart, Vinv);
    combine_w2<<<BHT, 256, 0, stream>>>(Opart, Spart, Vinv, W2);
    rows_fused<<<dim3(BHT, SEQ / 128), 256, 0, stream>>>(Qb, Kl, W2, Xp);

    gemm_bt<1><<<dim3(CH / 192, TOK / 128), 512, 0, stream>>>(
        Xp, wprojT, CH, CH, nullptr, nullptr, nullptr, nullptr, nullptr, out, b_proj);
}